// Round 12
// baseline (199.648 us; speedup 1.0000x reference)
//
#include <hip/hip_runtime.h>
#include <stdint.h>

#define T_SEQ 2048
#define D_MODEL 1024
#define NH 16
#define DH 64
#define NROWS 4096  // B*T

typedef __bf16 bf16x8 __attribute__((ext_vector_type(8)));
typedef float floatx4 __attribute__((ext_vector_type(4)));
typedef short short4v __attribute__((ext_vector_type(4)));
typedef short short8v __attribute__((ext_vector_type(8)));

#define AS1 __attribute__((address_space(1)))
#define AS3 __attribute__((address_space(3)))

static __device__ __forceinline__ void gl2lds16(const unsigned short* g, unsigned short* s) {
    __builtin_amdgcn_global_load_lds((const AS1 unsigned int*)g, (AS3 unsigned int*)s, 16, 0, 0);
}

static __device__ __forceinline__ unsigned short f32_bf16(float f) {
    union { float f; unsigned int u; } c; c.f = f;
    unsigned int u = c.u;
    u = u + 0x7FFFu + ((u >> 16) & 1u);   // RNE
    return (unsigned short)(u >> 16);
}

static __device__ __forceinline__ unsigned int pack2_bf16(float a, float b) {
    return (unsigned int)f32_bf16(a) | ((unsigned int)f32_bf16(b) << 16);
}

static __device__ __forceinline__ floatx4 mfma16(bf16x8 a, bf16x8 b, floatx4 c) {
    return __builtin_amdgcn_mfma_f32_16x16x32_bf16(a, b, c, 0, 0, 0);
}

static __device__ __forceinline__ bf16x8 as_bf(short8v s) {
    union { short8v s; bf16x8 b; } u; u.s = s; return u.b;
}

#define QSCALE 0.1803368801111204f   // (1/8) * log2(e); softmax in exp2 domain
#define EXP2_SHIFT 10.0f
// s_waitcnt imm: vmcnt[3:0], expcnt[6:4]=7 (nowait), lgkmcnt[11:8]=0xF (nowait)
#define WAITCNT_VM(n) (0x0F70 | (n))

// ---------------- fused conversion kernel ----------------
// Wo branch reads float4 coalesced and permutes via a 2KB LDS tile (r14).
__global__ __launch_bounds__(256) void k_conv_all(const float* __restrict__ x,
                                                  const float* __restrict__ Wq,
                                                  const float* __restrict__ Wk,
                                                  const float* __restrict__ Wv,
                                                  const float* __restrict__ Wo,
                                                  unsigned short* __restrict__ x_bf,
                                                  unsigned short* __restrict__ wqkv_bf,
                                                  unsigned short* __restrict__ wo_bf) {
    __shared__ unsigned short lt[1024];
    int b = blockIdx.x, t = threadIdx.x;
    if (b < 4096) {
        int i = b * 1024 + t * 4;
        float4 v = *(const float4*)(x + i);
        uint2 o;
        o.x = pack2_bf16(v.x, v.y);
        o.y = pack2_bf16(v.z, v.w);
        *(uint2*)(x_bf + i) = o;
    } else if (b < 7168) {
        int idx = b - 4096;
        int tensor = idx >> 10, np = idx & 1023;
        const float* src = tensor == 0 ? Wq : tensor == 1 ? Wk : Wv;
        int f = (np & 63) * 16 + (np >> 6);
        int c = t * 4;
        float4 v = *(const float4*)(src + (long)f * D_MODEL + c);
        uint2 o;
        o.x = pack2_bf16(v.x, v.y);
        o.y = pack2_bf16(v.z, v.w);
        *(uint2*)(wqkv_bf + ((long)tensor * D_MODEL + np) * D_MODEL + c) = o;
    } else {
        int n = b - 7168;
        const float* row = Wo + (long)n * D_MODEL;
        float4 v = *(const float4*)(row + t * 4);
        {
            int f = t * 4;
            lt[((f + 0) & 15) * 64 + ((f + 0) >> 4)] = f32_bf16(v.x);
            lt[((f + 1) & 15) * 64 + ((f + 1) >> 4)] = f32_bf16(v.y);
            lt[((f + 2) & 15) * 64 + ((f + 2) >> 4)] = f32_bf16(v.z);
            lt[((f + 3) & 15) * 64 + ((f + 3) >> 4)] = f32_bf16(v.w);
        }
        __syncthreads();
        *(uint2*)(wo_bf + (long)n * D_MODEL + t * 4) = *(const uint2*)(lt + t * 4);
    }
}

// ---------------- QKV GEMM: 256x192 tile, 8-wave, single-barrier K-tiles --------
// r17 structure (frozen): full-tile dbuf, 1 barrier/K-tile, LDS-routed Q/K
// epilogue (write amplification 40MB->24.6MB), V direct.
__global__ __launch_bounds__(512, 2) void k_qkv256(const unsigned short* __restrict__ A,
                                                   const unsigned short* __restrict__ W,
                                                   const float* __restrict__ bq,
                                                   const float* __restrict__ bk,
                                                   const float* __restrict__ bv,
                                                   unsigned short* __restrict__ out_bf,
                                                   unsigned short* __restrict__ vtg) {
    __shared__ unsigned short lds[2 * 28672];   // buf: A[256][64] | B[192][64]
    const int tid = threadIdx.x;
    const int w = tid >> 6, l = tid & 63;
    const int lrow = l & 15, lq = l >> 4;
    const int sw8 = lrow & 7;
    const int wm_id = w >> 2, wn_id = w & 3;
    const int L = blockIdx.x;
    const int bx = (L & 7) * 2 + ((L >> 3) & 1);   // 0..15
    const int by = L >> 4;                          // 0..15
    const long am0 = (long)bx * 256;
    const long wn0 = (long)by * 192;

    const int rl = l >> 3;                       // staging: row within 8-row chunk
    const int gl = ((l & 7) ^ rl) * 8;           // staging: swizzled granule (shorts)

    floatx4 acc[8][3] = {};

    // piece 0..3: A chunks; 4..6: B chunks. 1 DMA instr/thread/piece.
    auto stage_piece = [&](int ki, int sel, int piece) {
        int k0 = ki * 64;
        if (piece < 4) {
            int chunk = piece * 8 + w;           // 0..31 (8 rows each, 256 rows)
            gl2lds16(A + (am0 + chunk * 8 + rl) * D_MODEL + k0 + gl,
                     lds + sel * 28672 + chunk * 512);
        } else {
            int chunk = (piece - 4) * 8 + w;     // 0..23 (8 rows each, 192 rows)
            gl2lds16(W + (wn0 + chunk * 8 + rl) * D_MODEL + k0 + gl,
                     lds + sel * 28672 + 16384 + chunk * 512);
        }
    };

    // prologue: tile 0 fully staged
    #pragma unroll
    for (int pc = 0; pc < 7; pc++) stage_piece(0, 0, pc);
    __builtin_amdgcn_s_waitcnt(WAITCNT_VM(0));
    __builtin_amdgcn_s_barrier();

    for (int t = 0; t < 16; t++) {
        const int sel = t & 1;
        const unsigned short* Ab = lds + sel * 28672;
        const unsigned short* Bb = Ab + 16384;
        // issue ALL stage DMAs for tile t+1 up front (flight ~ full tile)
        if (t < 15) {
            #pragma unroll
            for (int pc = 0; pc < 7; pc++) stage_piece(t + 1, sel ^ 1, pc);
        }
        bf16x8 bfr[3];
        #pragma unroll
        for (int q = 0; q < 4; q++) {
            const int ks = q >> 1, mh = q & 1;
            if (mh == 0) {
                #pragma unroll
                for (int nt = 0; nt < 3; nt++) {
                    int row = wn_id * 48 + nt * 16 + lrow;
                    bfr[nt] = *(const bf16x8*)(Bb + row * 64 + (((ks * 4 + lq) ^ sw8) * 8));
                }
            }
            bf16x8 af[4];
            #pragma unroll
            for (int j = 0; j < 4; j++) {
                int row = wm_id * 128 + (mh * 4 + j) * 16 + lrow;
                af[j] = *(const bf16x8*)(Ab + row * 64 + (((ks * 4 + lq) ^ sw8) * 8));
            }
            __builtin_amdgcn_s_setprio(1);
            #pragma unroll
            for (int j = 0; j < 4; j++)
                #pragma unroll
                for (int nt = 0; nt < 3; nt++)
                    acc[mh * 4 + j][nt] = mfma16(af[j], bfr[nt], acc[mh * 4 + j][nt]);
            __builtin_amdgcn_s_setprio(0);
        }
        // tile boundary: own DMAs drained, then one barrier -> all waves' landed
        __builtin_amdgcn_s_waitcnt(WAITCNT_VM(0));
        __builtin_amdgcn_s_barrier();
    }

    // ---- epilogue ----
    // V: direct (single-wave-owned 128-B blocks). Q/K: deposit to LDS tile
    // [256][200] (pad +8 shorts breaks the 384-B power-stride), then
    // cooperative full-line uint4 stores.
    unsigned short* et = lds;                    // K-loop LDS dead after final barrier
    int row0 = (int)am0 + wm_id * 128;           // multiple of 128
    int bb_ = row0 >> 11;
    int blkb = (row0 & 2047) >> 6;
    #pragma unroll
    for (int nt = 0; nt < 3; nt++) {
        int n_local = wn_id * 48 + nt * 16 + lrow;
        int n = (int)wn0 + n_local;
        int tensor = n >> 10;                    // 0=Q 1=K 2=V (uniform per nt-tile)
        int np = n & 1023;                       // n' = h*64+d
        int h = np >> 6, d = np & 63;
        const float* bias = tensor == 0 ? bq : tensor == 1 ? bk : bv;
        float bbv = bias[d * 16 + h];
        float scale = tensor == 0 ? QSCALE : 1.0f;
        if (tensor < 2) {
            #pragma unroll
            for (int mt = 0; mt < 8; mt++) {
                #pragma unroll
                for (int r = 0; r < 4; r++) {
                    int il = wm_id * 128 + mt * 16 + lq * 4 + r;   // local row 0..255
                    et[il * 200 + n_local] = f32_bf16((acc[mt][nt][r] + bbv) * scale);
                }
            }
        } else {
            // vtg j'-slot permutation (within each 64-token block): position
            // g*32 + lq*8 + nt'*4 + r holds token (g*2+nt')*16 + lq*4 + r.
            #pragma unroll
            for (int mt = 0; mt < 8; mt++) {
                int blk = blkb + (mt >> 2);
                int m4 = mt & 3;
                long base = (((long)(bb_ * 16 + h) * 64 + d) * 32 + blk) * 64;
                uint2 o;
                o.x = pack2_bf16(acc[mt][nt][0] + bbv, acc[mt][nt][1] + bbv);
                o.y = pack2_bf16(acc[mt][nt][2] + bbv, acc[mt][nt][3] + bbv);
                *(uint2*)(vtg + base + (m4 >> 1) * 32 + lq * 8 + (m4 & 1) * 4) = o;
            }
        }
    }
    __syncthreads();
    // cooperative write-out: 256 rows x 24 chunks of 8 shorts; full 128-B lines
    // assembled across the 2 waves that produced them.
    #pragma unroll
    for (int k = 0; k < 12; k++) {
        int idx = tid + k * 512;                 // 0..6143
        int il = idx / 24, c = idx % 24;
        int n = (int)wn0 + c * 8;                // wn0 % 64 == 0 -> chunk within one h
        int tensor = n >> 10;
        if (tensor < 2) {
            int np = n & 1023;
            int h = np >> 6, d0 = np & 63;
            int row = (int)am0 + il;
            int b = row >> 11, i = row & 2047;
            unsigned short* outt = out_bf + (size_t)tensor * (32u * T_SEQ * DH);
            *(uint4*)(outt + ((long)(b * 16 + h) * T_SEQ + i) * DH + d0) =
                *(const uint4*)(et + il * 200 + c * 8);
        }
    }
}

// ---------------- O-proj GEMM: ring-3 LDS, 2-tile prefetch depth (r14) ----------------
template <int BN, int MODE>
__global__ __launch_bounds__(256) void k_gemm(const unsigned short* __restrict__ A,
                                              const unsigned short* __restrict__ W,
                                              const float* __restrict__ b0,
                                              const float* __restrict__ resid,
                                              float* __restrict__ out_f32) {
    constexpr int NT = BN / 32;
    constexpr int NCB = BN / 32;
    __shared__ unsigned short lds_a[3 * 128 * 64];
    __shared__ unsigned short lds_b[3 * BN * 64];
    const int tid = threadIdx.x;
    const int w = tid >> 6, l = tid & 63;
    const int lrow = l & 15, lq = l >> 4;
    const int wm = (w >> 1) * 64, wn = (w & 1) * (BN / 2);
    const int L = blockIdx.x;
    const int bx = (L & 7) * 4 + ((L >> 3) & 3);
    const int by = L >> 5;
    const long am0 = (long)bx * 128;
    const long wn0 = (long)by * BN;

    floatx4 acc[4][NT] = {};
    const int grow = l >> 3;
    const int gcol = ((l & 7) ^ grow) * 8;   // column-group XOR swizzle (global side)
    const int sw8 = (lrow & 7);

    auto stage = [&](int ki, int sel) {
        unsigned short* la = lds_a + sel * 8192;
        unsigned short* lb = lds_b + sel * (BN * 64);
        int k0 = ki * 64;
        #pragma unroll
        for (int c = 0; c < 4; c++) {
            int chunk = w * 4 + c;
            gl2lds16(A + (am0 + chunk * 8 + grow) * D_MODEL + k0 + gcol, la + chunk * 512);
        }
        #pragma unroll
        for (int c = 0; c < NCB; c++) {
            int chunk = w * NCB + c;
            gl2lds16(W + (wn0 + chunk * 8 + grow) * D_MODEL + k0 + gcol, lb + chunk * 512);
        }
    };

    auto compute = [&](const unsigned short* la, const unsigned short* lb) {
        bf16x8 af[4][2], bfr[NT][2];
        #pragma unroll
        for (int mt = 0; mt < 4; mt++)
            #pragma unroll
            for (int ks = 0; ks < 2; ks++)
                af[mt][ks] = *(const bf16x8*)(la + (wm + mt * 16 + lrow) * 64 +
                                              (((ks * 4 + lq) ^ sw8) * 8));
        #pragma unroll
        for (int nt = 0; nt < NT; nt++)
            #pragma unroll
            for (int ks = 0; ks < 2; ks++)
                bfr[nt][ks] = *(const bf16x8*)(lb + (wn + nt * 16 + lrow) * 64 +
                                               (((ks * 4 + lq) ^ sw8) * 8));
        #pragma unroll
        for (int mt = 0; mt < 4; mt++)
            #pragma unroll
            for (int nt = 0; nt < NT; nt++)
                #pragma unroll
                for (int ks = 0; ks < 2; ks++)
                    acc[mt][nt] = mfma16(af[mt][ks], bfr[nt][ks], acc[mt][nt]);
    };

    stage(0, 0);
    stage(1, 1);
    for (int i = 0; i < 16; i++) {
        const int sel = i % 3;
        if (i < 14) {
            stage(i + 2, (i + 2) % 3);
            __builtin_amdgcn_s_waitcnt(WAITCNT_VM(12));  // drain S(i), keep S(i+1),S(i+2)
        } else if (i == 14) {
            __builtin_amdgcn_s_waitcnt(WAITCNT_VM(6));   // drain S(14), keep S(15)
        } else {
            __builtin_amdgcn_s_waitcnt(WAITCNT_VM(0));   // drain S(15)
        }
        __builtin_amdgcn_s_barrier();
        compute(lds_a + sel * 8192, lds_b + sel * (BN * 64));
        __builtin_amdgcn_s_barrier();   // certifies compute(i) done -> slot i%3 reusable by S(i+3)
    }

    #pragma unroll
    for (int mt = 0; mt < 4; mt++) {
        #pragma unroll
        for (int nt = 0; nt < NT; nt++) {
            int n = (int)wn0 + wn + nt * 16 + lrow;
            float bb = b0[n];
            #pragma unroll
            for (int r = 0; r < 4; r++) {
                int row = (int)am0 + wm + mt * 16 + lq * 4 + r;
                long idx = (long)row * D_MODEL + n;
                out_f32[idx] = acc[mt][nt][r] + bb + resid[idx];
            }
        }
    }
}

// ---------------- attention: QBLK=64, ring-3 LDS, 3 blocks/CU ----------------
// r18: the two waves/SIMD were barrier-locked in phase -> MFMA (35%) and
// VALU/TRANS (43%) bursts serialized (sum ~83% of duration). Halve the Q-block
// (64 rows, grid 1024) and shrink the K/V ring to 3 slots (48 KB LDS) ->
// 3 blocks/CU, 3 waves/SIMD with independent phases packing both pipes.
// Ring-3 safety: stage(t+2)->slot (t+2)%3 = body(t-1)'s slot, issued AFTER
// barrier(t) which certifies all waves finished body(t-1); concurrent body(t)
// readers use slot t%3. Ledger: outstanding at vmcnt = {S(t),S(t+1)} = 8 ->
// vmcnt(4) drains exactly S(t); t=31 -> vmcnt(0). Per-q-row math identical
// (one q-tile/wave instead of two) -> bitwise-identical output.
__global__ __launch_bounds__(256) void k_attn(const unsigned short* __restrict__ q_ws,
                                              const unsigned short* __restrict__ k_ws,
                                              const unsigned short* __restrict__ vtg,
                                              unsigned short* __restrict__ att) {
    __shared__ unsigned short kbuf[3 * 4096];
    __shared__ unsigned short vbuf[3 * 4096];
    const int tid = threadIdx.x;
    const int w = tid >> 6, l = tid & 63;
    const int lrow = l & 15, lq = l >> 4;
    const int sw = lrow & 7;
    const int L = blockIdx.x;
    const int bh = (L & 7) * 4 + ((L >> 3) & 3);   // 4 bh per XCD -> K/V L2-resident
    const int i0 = (L >> 5) * 64;                  // 32 q-blocks of 64 rows
    const unsigned short* kh = k_ws + (long)bh * T_SEQ * DH;
    const unsigned short* vh = vtg + (long)bh * 64 * T_SEQ;  // [d][blk][j'-permuted]

    const int rl = l >> 3;                     // staging: row within 8-row chunk
    const int gl = ((l & 7) ^ rl) * 8;         // staging: swizzled granule (shorts)

    bf16x8 qf[2];
    {
        const unsigned short* qp =
            q_ws + ((long)bh * T_SEQ + i0 + w * 16 + lrow) * DH + lq * 8;
        qf[0] = *(const bf16x8*)qp;
        qf[1] = *(const bf16x8*)(qp + 32);
    }
    floatx4 o_acc[4] = {};
    floatx4 l_acc = {};
    const short8v ones8s = {0x3F80, 0x3F80, 0x3F80, 0x3F80, 0x3F80, 0x3F80, 0x3F80, 0x3F80};
    const bf16x8 ones8 = as_bf(ones8s);

    // one K/V tile stage: 4 DMA instrs per thread (2 K + 2 V)
    auto stage = [&](int jt, int sel) {
        unsigned short* kd = kbuf + sel * 4096 + (w * 2) * 512;
        unsigned short* vd = vbuf + sel * 4096 + (w * 2) * 512;
        #pragma unroll
        for (int c = 0; c < 2; c++) {
            int row = w * 16 + c * 8 + rl;     // 0..63
            gl2lds16(kh + ((long)(jt * 64 + row)) * 64 + gl, kd + c * 512);
        }
        #pragma unroll
        for (int c = 0; c < 2; c++) {
            int row = w * 16 + c * 8 + rl;
            gl2lds16(vh + ((long)row * 32 + jt) * 64 + gl, vd + c * 512);
        }
    };

    // p = exp2(s); pack 4 bf16 (truncation via perm)
    auto sp4 = [&](floatx4 s) -> short4v {
        float p0 = __builtin_amdgcn_exp2f(s[0]);
        float p1 = __builtin_amdgcn_exp2f(s[1]);
        float p2 = __builtin_amdgcn_exp2f(s[2]);
        float p3 = __builtin_amdgcn_exp2f(s[3]);
        uint2 pk;
        pk.x = __builtin_amdgcn_perm(__float_as_uint(p1), __float_as_uint(p0), 0x07060302);
        pk.y = __builtin_amdgcn_perm(__float_as_uint(p3), __float_as_uint(p2), 0x07060302);
        union { uint2 u; short4v s4; } cv; cv.u = pk;
        return cv.s4;
    };

    stage(0, 0);
    stage(1, 1);

    for (int t = 0; t < 32; t++) {
        const int sl = t % 3;
        if (t < 31)
            __builtin_amdgcn_s_waitcnt(WAITCNT_VM(4));   // drain S(t), keep S(t+1)
        else
            __builtin_amdgcn_s_waitcnt(WAITCNT_VM(0));   // drain S(31)
        __builtin_amdgcn_s_barrier();                    // all waves' S(t) landed
        if (t < 30) stage(t + 2, (t + 2) % 3);           // slot = body(t-1)'s, certified free

        const unsigned short* kb_ = kbuf + sl * 4096;
        const unsigned short* vb_ = vbuf + sl * 4096;

        // QK^T with sp4 of the previous nt-group interleaved (TRANS under MFMA)
        floatx4 s0[4];
        short4v u0[4];
        #pragma unroll
        for (int nt = 0; nt < 4; nt++) {
            const unsigned short* kp = kb_ + (nt * 16 + lrow) * 64;
            bf16x8 ka = *(const bf16x8*)(kp + ((lq ^ sw) * 8));
            bf16x8 kb2 = *(const bf16x8*)(kp + (((lq + 4) ^ sw) * 8));
            floatx4 c0 = {-EXP2_SHIFT, -EXP2_SHIFT, -EXP2_SHIFT, -EXP2_SHIFT};
            c0 = mfma16(ka, qf[0], c0);
            c0 = mfma16(kb2, qf[1], c0);
            s0[nt] = c0;
            if (nt > 0) u0[nt - 1] = sp4(s0[nt - 1]);
        }
        u0[3] = sp4(s0[3]);
        short8v pf0[2];
        pf0[0] = __builtin_shufflevector(u0[0], u0[1], 0, 1, 2, 3, 4, 5, 6, 7);
        pf0[1] = __builtin_shufflevector(u0[2], u0[3], 0, 1, 2, 3, 4, 5, 6, 7);
        // pure-MFMA burst: l_acc (2) + PV (8) — boost arbitration priority
        __builtin_amdgcn_s_setprio(1);
        l_acc = mfma16(ones8, as_bf(pf0[0]), l_acc);
        l_acc = mfma16(ones8, as_bf(pf0[1]), l_acc);
        #pragma unroll
        for (int dt = 0; dt < 4; dt++) {
            const unsigned short* vp = vb_ + (dt * 16 + lrow) * 64;
            bf16x8 vg0 = *(const bf16x8*)(vp + ((lq ^ sw) * 8));       // j 0..31
            bf16x8 vg1 = *(const bf16x8*)(vp + (((4 + lq) ^ sw) * 8)); // j 32..63
            o_acc[dt] = mfma16(vg0, as_bf(pf0[0]), o_acc[dt]);
            o_acc[dt] = mfma16(vg1, as_bf(pf0[1]), o_acc[dt]);
        }
        __builtin_amdgcn_s_setprio(0);
        // no trailing barrier: ring-3 slot discipline covers restage safety
    }

    int h = bh & 15, b = bh >> 4;
    {
        float rl2 = 1.0f / l_acc[0];
        int i = i0 + w * 16 + lrow;
        unsigned short* orow = att + ((long)(b * T_SEQ + i)) * D_MODEL + h * 64;
        #pragma unroll
        for (int dt = 0; dt < 4; dt++) {
            uint2 o;
            o.x = pack2_bf16(o_acc[dt][0] * rl2, o_acc[dt][1] * rl2);
            o.y = pack2_bf16(o_acc[dt][2] * rl2, o_acc[dt][3] * rl2);
            *(uint2*)(orow + dt * 16 + lq * 4) = o;
        }
    }
}

// ---------------- LayerNorm in-place on d_out ----------------
__global__ __launch_bounds__(256) void k_ln(float* __restrict__ io,
                                            const float* __restrict__ gamma,
                                            const float* __restrict__ beta) {
    int row = blockIdx.x, t = threadIdx.x;
    float* p = io + (long)row * D_MODEL + t * 4;
    float4 v = *(float4*)p;
    float s = v.x + v.y + v.z + v.w;
    float ss = v.x * v.x + v.y * v.y + v.z * v.z + v.w * v.w;
    #pragma unroll
    for (int m = 1; m < 64; m <<= 1) {
        s += __shfl_xor(s, m);
        ss += __shfl_xor(ss, m);
    }
    __shared__ float red[8];
    if ((t & 63) == 0) { red[t >> 6] = s; red[4 + (t >> 6)] = ss; }
    __syncthreads();
    s = red[0] + red[1] + red[2] + red[3];
    ss = red[4] + red[5] + red[6] + red[7];
    float mu = s * (1.0f / 1024.0f);
    float var = ss * (1.0f / 1024.0f) - mu * mu;
    float rstd = rsqrtf(var + 1e-5f);
    float4 g = *(const float4*)(gamma + t * 4);
    float4 be = *(const float4*)(beta + t * 4);
    float4 o;
    o.x = (v.x - mu) * rstd * g.x + be.x;
    o.y = (v.y - mu) * rstd * g.y + be.y;
    o.z = (v.z - mu) * rstd * g.z + be.z;
    o.w = (v.w - mu) * rstd * g.w + be.w;
    *(float4*)p = o;
}

extern "C" void kernel_launch(void* const* d_in, const int* in_sizes, int n_in,
                              void* d_out, int out_size, void* d_ws, size_t ws_size,
                              hipStream_t stream) {
    const float* x = (const float*)d_in[0];
    const float* Wq = (const float*)d_in[1];
    const float* bq = (const float*)d_in[2];
    const float* Wk = (const float*)d_in[3];
    const float* bk = (const float*)d_in[4];
    const float* Wv = (const float*)d_in[5];
    const float* bv = (const float*)d_in[6];
    const float* Wo = (const float*)d_in[7];
    const float* bo = (const float*)d_in[8];
    const float* gamma = (const float*)d_in[9];
    const float* beta = (const float*)d_in[10];
    float* out = (float*)d_out;

    char* ws = (char*)d_ws;
    unsigned short* x_bf = (unsigned short*)(ws);                       // 0-8 MB (reused as att)
    unsigned short* wqkv_bf = (unsigned short*)(ws + ((size_t)8 << 20));// 8-14 MB
    unsigned short* wo_bf = (unsigned short*)(ws + ((size_t)14 << 20)); // 14-16 MB
    unsigned short* qkv_ws = (unsigned short*)(ws + ((size_t)16 << 20));// 16-40 MB (q|k|vt)
    unsigned short* att = x_bf;  // alias: x_bf dead after QKV GEMM

    unsigned short* q_ws = qkv_ws;
    unsigned short* k_ws = qkv_ws + (size_t)32 * T_SEQ * DH;
    unsigned short* vtg = qkv_ws + (size_t)64 * T_SEQ * DH;

    k_conv_all<<<8192, 256, 0, stream>>>(x, Wq, Wk, Wv, Wo, x_bf, wqkv_bf, wo_bf);

    // fused QKV GEMM: 256x192 tiles, N = 3072, grid 256 (16x16, XCD-interleaved)
    k_qkv256<<<256, 512, 0, stream>>>(x_bf, wqkv_bf, bq, bk, bv, qkv_ws, vtg);

    // attention: QBLK=64, grid 1024 (32 bh x 32 q-blocks), 3 blocks/CU
    k_attn<<<1024, 256, 0, stream>>>(q_ws, k_ws, vtg, att);

    // O-projection + bias + residual: N = 1024, 1D grid with XCD swizzle
    k_gemm<64, 1><<<512, 256, 0, stream>>>(
        att, wo_bf, bo, x, out);

    k_ln<<<NROWS, 256, 0, stream>>>(out, gamma, beta);
}

// Round 13
// 181.558 us; speedup vs baseline: 1.0996x; 1.0996x over previous
//
#include <hip/hip_runtime.h>
#include <stdint.h>

#define T_SEQ 2048
#define D_MODEL 1024
#define NH 16
#define DH 64
#define NROWS 4096  // B*T

typedef __bf16 bf16x8 __attribute__((ext_vector_type(8)));
typedef float floatx4 __attribute__((ext_vector_type(4)));
typedef short short4v __attribute__((ext_vector_type(4)));
typedef short short8v __attribute__((ext_vector_type(8)));

#define AS1 __attribute__((address_space(1)))
#define AS3 __attribute__((address_space(3)))

static __device__ __forceinline__ void gl2lds16(const unsigned short* g, unsigned short* s) {
    __builtin_amdgcn_global_load_lds((const AS1 unsigned int*)g, (AS3 unsigned int*)s, 16, 0, 0);
}

static __device__ __forceinline__ unsigned short f32_bf16(float f) {
    union { float f; unsigned int u; } c; c.f = f;
    unsigned int u = c.u;
    u = u + 0x7FFFu + ((u >> 16) & 1u);   // RNE
    return (unsigned short)(u >> 16);
}

static __device__ __forceinline__ unsigned int pack2_bf16(float a, float b) {
    return (unsigned int)f32_bf16(a) | ((unsigned int)f32_bf16(b) << 16);
}

static __device__ __forceinline__ floatx4 mfma16(bf16x8 a, bf16x8 b, floatx4 c) {
    return __builtin_amdgcn_mfma_f32_16x16x32_bf16(a, b, c, 0, 0, 0);
}

static __device__ __forceinline__ bf16x8 as_bf(short8v s) {
    union { short8v s; bf16x8 b; } u; u.s = s; return u.b;
}

#define QSCALE 0.1803368801111204f   // (1/8) * log2(e); softmax in exp2 domain
#define EXP2_SHIFT 10.0f
// s_waitcnt imm: vmcnt[3:0], expcnt[6:4]=7 (nowait), lgkmcnt[11:8]=0xF (nowait)
#define WAITCNT_VM(n) (0x0F70 | (n))

// ---------------- fused conversion kernel ----------------
// Wo branch reads float4 coalesced and permutes via a 2KB LDS tile (r14).
__global__ __launch_bounds__(256) void k_conv_all(const float* __restrict__ x,
                                                  const float* __restrict__ Wq,
                                                  const float* __restrict__ Wk,
                                                  const float* __restrict__ Wv,
                                                  const float* __restrict__ Wo,
                                                  unsigned short* __restrict__ x_bf,
                                                  unsigned short* __restrict__ wqkv_bf,
                                                  unsigned short* __restrict__ wo_bf) {
    __shared__ unsigned short lt[1024];
    int b = blockIdx.x, t = threadIdx.x;
    if (b < 4096) {
        int i = b * 1024 + t * 4;
        float4 v = *(const float4*)(x + i);
        uint2 o;
        o.x = pack2_bf16(v.x, v.y);
        o.y = pack2_bf16(v.z, v.w);
        *(uint2*)(x_bf + i) = o;
    } else if (b < 7168) {
        int idx = b - 4096;
        int tensor = idx >> 10, np = idx & 1023;
        const float* src = tensor == 0 ? Wq : tensor == 1 ? Wk : Wv;
        int f = (np & 63) * 16 + (np >> 6);
        int c = t * 4;
        float4 v = *(const float4*)(src + (long)f * D_MODEL + c);
        uint2 o;
        o.x = pack2_bf16(v.x, v.y);
        o.y = pack2_bf16(v.z, v.w);
        *(uint2*)(wqkv_bf + ((long)tensor * D_MODEL + np) * D_MODEL + c) = o;
    } else {
        int n = b - 7168;
        const float* row = Wo + (long)n * D_MODEL;
        float4 v = *(const float4*)(row + t * 4);
        {
            int f = t * 4;
            lt[((f + 0) & 15) * 64 + ((f + 0) >> 4)] = f32_bf16(v.x);
            lt[((f + 1) & 15) * 64 + ((f + 1) >> 4)] = f32_bf16(v.y);
            lt[((f + 2) & 15) * 64 + ((f + 2) >> 4)] = f32_bf16(v.z);
            lt[((f + 3) & 15) * 64 + ((f + 3) >> 4)] = f32_bf16(v.w);
        }
        __syncthreads();
        *(uint2*)(wo_bf + (long)n * D_MODEL + t * 4) = *(const uint2*)(lt + t * 4);
    }
}

// ---------------- QKV GEMM: 256x192 tile, 8-wave, single-barrier K-tiles --------
// r17 structure (frozen): full-tile dbuf, 1 barrier/K-tile, LDS-routed Q/K
// epilogue (write amplification 40MB->24.6MB), V direct.
__global__ __launch_bounds__(512, 2) void k_qkv256(const unsigned short* __restrict__ A,
                                                   const unsigned short* __restrict__ W,
                                                   const float* __restrict__ bq,
                                                   const float* __restrict__ bk,
                                                   const float* __restrict__ bv,
                                                   unsigned short* __restrict__ out_bf,
                                                   unsigned short* __restrict__ vtg) {
    __shared__ unsigned short lds[2 * 28672];   // buf: A[256][64] | B[192][64]
    const int tid = threadIdx.x;
    const int w = tid >> 6, l = tid & 63;
    const int lrow = l & 15, lq = l >> 4;
    const int sw8 = lrow & 7;
    const int wm_id = w >> 2, wn_id = w & 3;
    const int L = blockIdx.x;
    const int bx = (L & 7) * 2 + ((L >> 3) & 1);   // 0..15
    const int by = L >> 4;                          // 0..15
    const long am0 = (long)bx * 256;
    const long wn0 = (long)by * 192;

    const int rl = l >> 3;                       // staging: row within 8-row chunk
    const int gl = ((l & 7) ^ rl) * 8;           // staging: swizzled granule (shorts)

    floatx4 acc[8][3] = {};

    // piece 0..3: A chunks; 4..6: B chunks. 1 DMA instr/thread/piece.
    auto stage_piece = [&](int ki, int sel, int piece) {
        int k0 = ki * 64;
        if (piece < 4) {
            int chunk = piece * 8 + w;           // 0..31 (8 rows each, 256 rows)
            gl2lds16(A + (am0 + chunk * 8 + rl) * D_MODEL + k0 + gl,
                     lds + sel * 28672 + chunk * 512);
        } else {
            int chunk = (piece - 4) * 8 + w;     // 0..23 (8 rows each, 192 rows)
            gl2lds16(W + (wn0 + chunk * 8 + rl) * D_MODEL + k0 + gl,
                     lds + sel * 28672 + 16384 + chunk * 512);
        }
    };

    // prologue: tile 0 fully staged
    #pragma unroll
    for (int pc = 0; pc < 7; pc++) stage_piece(0, 0, pc);
    __builtin_amdgcn_s_waitcnt(WAITCNT_VM(0));
    __builtin_amdgcn_s_barrier();

    for (int t = 0; t < 16; t++) {
        const int sel = t & 1;
        const unsigned short* Ab = lds + sel * 28672;
        const unsigned short* Bb = Ab + 16384;
        // issue ALL stage DMAs for tile t+1 up front (flight ~ full tile)
        if (t < 15) {
            #pragma unroll
            for (int pc = 0; pc < 7; pc++) stage_piece(t + 1, sel ^ 1, pc);
        }
        bf16x8 bfr[3];
        #pragma unroll
        for (int q = 0; q < 4; q++) {
            const int ks = q >> 1, mh = q & 1;
            if (mh == 0) {
                #pragma unroll
                for (int nt = 0; nt < 3; nt++) {
                    int row = wn_id * 48 + nt * 16 + lrow;
                    bfr[nt] = *(const bf16x8*)(Bb + row * 64 + (((ks * 4 + lq) ^ sw8) * 8));
                }
            }
            bf16x8 af[4];
            #pragma unroll
            for (int j = 0; j < 4; j++) {
                int row = wm_id * 128 + (mh * 4 + j) * 16 + lrow;
                af[j] = *(const bf16x8*)(Ab + row * 64 + (((ks * 4 + lq) ^ sw8) * 8));
            }
            __builtin_amdgcn_s_setprio(1);
            #pragma unroll
            for (int j = 0; j < 4; j++)
                #pragma unroll
                for (int nt = 0; nt < 3; nt++)
                    acc[mh * 4 + j][nt] = mfma16(af[j], bfr[nt], acc[mh * 4 + j][nt]);
            __builtin_amdgcn_s_setprio(0);
        }
        // tile boundary: own DMAs drained, then one barrier -> all waves' landed
        __builtin_amdgcn_s_waitcnt(WAITCNT_VM(0));
        __builtin_amdgcn_s_barrier();
    }

    // ---- epilogue ----
    // V: direct (single-wave-owned 128-B blocks). Q/K: deposit to LDS tile
    // [256][200] (pad +8 shorts breaks the 384-B power-stride), then
    // cooperative full-line uint4 stores.
    unsigned short* et = lds;                    // K-loop LDS dead after final barrier
    int row0 = (int)am0 + wm_id * 128;           // multiple of 128
    int bb_ = row0 >> 11;
    int blkb = (row0 & 2047) >> 6;
    #pragma unroll
    for (int nt = 0; nt < 3; nt++) {
        int n_local = wn_id * 48 + nt * 16 + lrow;
        int n = (int)wn0 + n_local;
        int tensor = n >> 10;                    // 0=Q 1=K 2=V (uniform per nt-tile)
        int np = n & 1023;                       // n' = h*64+d
        int h = np >> 6, d = np & 63;
        const float* bias = tensor == 0 ? bq : tensor == 1 ? bk : bv;
        float bbv = bias[d * 16 + h];
        float scale = tensor == 0 ? QSCALE : 1.0f;
        if (tensor < 2) {
            #pragma unroll
            for (int mt = 0; mt < 8; mt++) {
                #pragma unroll
                for (int r = 0; r < 4; r++) {
                    int il = wm_id * 128 + mt * 16 + lq * 4 + r;   // local row 0..255
                    et[il * 200 + n_local] = f32_bf16((acc[mt][nt][r] + bbv) * scale);
                }
            }
        } else {
            // vtg j'-slot permutation (within each 64-token block): position
            // g*32 + lq*8 + nt'*4 + r holds token (g*2+nt')*16 + lq*4 + r.
            #pragma unroll
            for (int mt = 0; mt < 8; mt++) {
                int blk = blkb + (mt >> 2);
                int m4 = mt & 3;
                long base = (((long)(bb_ * 16 + h) * 64 + d) * 32 + blk) * 64;
                uint2 o;
                o.x = pack2_bf16(acc[mt][nt][0] + bbv, acc[mt][nt][1] + bbv);
                o.y = pack2_bf16(acc[mt][nt][2] + bbv, acc[mt][nt][3] + bbv);
                *(uint2*)(vtg + base + (m4 >> 1) * 32 + lq * 8 + (m4 & 1) * 4) = o;
            }
        }
    }
    __syncthreads();
    // cooperative write-out: 256 rows x 24 chunks of 8 shorts; full 128-B lines
    // assembled across the 2 waves that produced them.
    #pragma unroll
    for (int k = 0; k < 12; k++) {
        int idx = tid + k * 512;                 // 0..6143
        int il = idx / 24, c = idx % 24;
        int n = (int)wn0 + c * 8;                // wn0 % 64 == 0 -> chunk within one h
        int tensor = n >> 10;
        if (tensor < 2) {
            int np = n & 1023;
            int h = np >> 6, d0 = np & 63;
            int row = (int)am0 + il;
            int b = row >> 11, i = row & 2047;
            unsigned short* outt = out_bf + (size_t)tensor * (32u * T_SEQ * DH);
            *(uint4*)(outt + ((long)(b * 16 + h) * T_SEQ + i) * DH + d0) =
                *(const uint4*)(et + il * 200 + c * 8);
        }
    }
}

// ---------------- O-proj GEMM: ring-3 LDS, 2-tile prefetch depth (r14) ----------------
template <int BN, int MODE>
__global__ __launch_bounds__(256) void k_gemm(const unsigned short* __restrict__ A,
                                              const unsigned short* __restrict__ W,
                                              const float* __restrict__ b0,
                                              const float* __restrict__ resid,
                                              float* __restrict__ out_f32) {
    constexpr int NT = BN / 32;
    constexpr int NCB = BN / 32;
    __shared__ unsigned short lds_a[3 * 128 * 64];
    __shared__ unsigned short lds_b[3 * BN * 64];
    const int tid = threadIdx.x;
    const int w = tid >> 6, l = tid & 63;
    const int lrow = l & 15, lq = l >> 4;
    const int wm = (w >> 1) * 64, wn = (w & 1) * (BN / 2);
    const int L = blockIdx.x;
    const int bx = (L & 7) * 4 + ((L >> 3) & 3);
    const int by = L >> 5;
    const long am0 = (long)bx * 128;
    const long wn0 = (long)by * BN;

    floatx4 acc[4][NT] = {};
    const int grow = l >> 3;
    const int gcol = ((l & 7) ^ grow) * 8;   // column-group XOR swizzle (global side)
    const int sw8 = (lrow & 7);

    auto stage = [&](int ki, int sel) {
        unsigned short* la = lds_a + sel * 8192;
        unsigned short* lb = lds_b + sel * (BN * 64);
        int k0 = ki * 64;
        #pragma unroll
        for (int c = 0; c < 4; c++) {
            int chunk = w * 4 + c;
            gl2lds16(A + (am0 + chunk * 8 + grow) * D_MODEL + k0 + gcol, la + chunk * 512);
        }
        #pragma unroll
        for (int c = 0; c < NCB; c++) {
            int chunk = w * NCB + c;
            gl2lds16(W + (wn0 + chunk * 8 + grow) * D_MODEL + k0 + gcol, lb + chunk * 512);
        }
    };

    auto compute = [&](const unsigned short* la, const unsigned short* lb) {
        bf16x8 af[4][2], bfr[NT][2];
        #pragma unroll
        for (int mt = 0; mt < 4; mt++)
            #pragma unroll
            for (int ks = 0; ks < 2; ks++)
                af[mt][ks] = *(const bf16x8*)(la + (wm + mt * 16 + lrow) * 64 +
                                              (((ks * 4 + lq) ^ sw8) * 8));
        #pragma unroll
        for (int nt = 0; nt < NT; nt++)
            #pragma unroll
            for (int ks = 0; ks < 2; ks++)
                bfr[nt][ks] = *(const bf16x8*)(lb + (wn + nt * 16 + lrow) * 64 +
                                               (((ks * 4 + lq) ^ sw8) * 8));
        #pragma unroll
        for (int mt = 0; mt < 4; mt++)
            #pragma unroll
            for (int nt = 0; nt < NT; nt++)
                #pragma unroll
                for (int ks = 0; ks < 2; ks++)
                    acc[mt][nt] = mfma16(af[mt][ks], bfr[nt][ks], acc[mt][nt]);
    };

    stage(0, 0);
    stage(1, 1);
    for (int i = 0; i < 16; i++) {
        const int sel = i % 3;
        if (i < 14) {
            stage(i + 2, (i + 2) % 3);
            __builtin_amdgcn_s_waitcnt(WAITCNT_VM(12));  // drain S(i), keep S(i+1),S(i+2)
        } else if (i == 14) {
            __builtin_amdgcn_s_waitcnt(WAITCNT_VM(6));   // drain S(14), keep S(15)
        } else {
            __builtin_amdgcn_s_waitcnt(WAITCNT_VM(0));   // drain S(15)
        }
        __builtin_amdgcn_s_barrier();
        compute(lds_a + sel * 8192, lds_b + sel * (BN * 64));
        __builtin_amdgcn_s_barrier();   // certifies compute(i) done -> slot i%3 reusable by S(i+3)
    }

    #pragma unroll
    for (int mt = 0; mt < 4; mt++) {
        #pragma unroll
        for (int nt = 0; nt < NT; nt++) {
            int n = (int)wn0 + wn + nt * 16 + lrow;
            float bb = b0[n];
            #pragma unroll
            for (int r = 0; r < 4; r++) {
                int row = (int)am0 + wm + mt * 16 + lq * 4 + r;
                long idx = (long)row * D_MODEL + n;
                out_f32[idx] = acc[mt][nt][r] + bb + resid[idx];
            }
        }
    }
}

// ---------------- attention: ring-4 LDS + single-barrier counted-vmcnt pipeline --------
// r13 structure RESTORED verbatim (measured 44.0/46.2/43.9 across rounds 7/9/11).
// r18's QBLK=64/ring-3 restructure regressed to 67-73us: grid 1024 at 3-block/CU
// capacity = 1.33 dispatch rounds (ragged tail), halved per-tile body work vs
// constant per-tile fixed costs, and stage-after-barrier cut DMA flight to ~1
// body. Occupancy restructures of this structure are falsified (r6, r18);
// ~44us is its plateau.
__global__ __launch_bounds__(256) void k_attn(const unsigned short* __restrict__ q_ws,
                                              const unsigned short* __restrict__ k_ws,
                                              const unsigned short* __restrict__ vtg,
                                              unsigned short* __restrict__ att) {
    __shared__ unsigned short kbuf[4 * 4096];
    __shared__ unsigned short vbuf[4 * 4096];
    const int tid = threadIdx.x;
    const int w = tid >> 6, l = tid & 63;
    const int lrow = l & 15, lq = l >> 4;
    const int sw = lrow & 7;
    const int L = blockIdx.x;
    const int bh = (L & 7) * 4 + ((L >> 3) & 3);   // 4 bh per XCD -> K/V L2-resident
    const int i0 = (L >> 5) * 128;
    const unsigned short* kh = k_ws + (long)bh * T_SEQ * DH;
    const unsigned short* vh = vtg + (long)bh * 64 * T_SEQ;  // [d][blk][j'-permuted]

    const int rl = l >> 3;                     // staging: row within 8-row chunk
    const int gl = ((l & 7) ^ rl) * 8;         // staging: swizzled granule (shorts)

    bf16x8 qf[2][2];
    #pragma unroll
    for (int qt = 0; qt < 2; qt++) {
        const unsigned short* qp =
            q_ws + ((long)bh * T_SEQ + i0 + w * 32 + qt * 16 + lrow) * DH + lq * 8;
        qf[qt][0] = *(const bf16x8*)qp;
        qf[qt][1] = *(const bf16x8*)(qp + 32);
    }
    floatx4 o_acc[2][4] = {};
    floatx4 l_acc[2] = {};
    const short8v ones8s = {0x3F80, 0x3F80, 0x3F80, 0x3F80, 0x3F80, 0x3F80, 0x3F80, 0x3F80};
    const bf16x8 ones8 = as_bf(ones8s);

    // one K/V tile stage: 4 DMA instrs per thread (2 K + 2 V)
    auto stage = [&](int jt, int sel) {
        unsigned short* kd = kbuf + sel * 4096 + (w * 2) * 512;
        unsigned short* vd = vbuf + sel * 4096 + (w * 2) * 512;
        #pragma unroll
        for (int c = 0; c < 2; c++) {
            int row = w * 16 + c * 8 + rl;     // 0..63
            gl2lds16(kh + ((long)(jt * 64 + row)) * 64 + gl, kd + c * 512);
        }
        #pragma unroll
        for (int c = 0; c < 2; c++) {
            int row = w * 16 + c * 8 + rl;
            gl2lds16(vh + ((long)row * 32 + jt) * 64 + gl, vd + c * 512);
        }
    };

    // p = exp2(s); pack 4 bf16 (truncation via perm)
    auto sp4 = [&](floatx4 s) -> short4v {
        float p0 = __builtin_amdgcn_exp2f(s[0]);
        float p1 = __builtin_amdgcn_exp2f(s[1]);
        float p2 = __builtin_amdgcn_exp2f(s[2]);
        float p3 = __builtin_amdgcn_exp2f(s[3]);
        uint2 pk;
        pk.x = __builtin_amdgcn_perm(__float_as_uint(p1), __float_as_uint(p0), 0x07060302);
        pk.y = __builtin_amdgcn_perm(__float_as_uint(p3), __float_as_uint(p2), 0x07060302);
        union { uint2 u; short4v s4; } cv; cv.u = pk;
        return cv.s4;
    };

    // O^T += V^T * P for one dt, both q-tiles, K=32 (two j-halves g=0/1)
    auto pv_dt = [&](const unsigned short* vb_, int dt,
                     short8v (&p0)[2], short8v (&p1)[2]) {
        const unsigned short* vp = vb_ + (dt * 16 + lrow) * 64;
        bf16x8 vg0 = *(const bf16x8*)(vp + ((lq ^ sw) * 8));         // granule lq   (j 0..31)
        bf16x8 vg1 = *(const bf16x8*)(vp + (((4 + lq) ^ sw) * 8));   // granule 4+lq (j 32..63)
        o_acc[0][dt] = mfma16(vg0, as_bf(p0[0]), o_acc[0][dt]);
        o_acc[0][dt] = mfma16(vg1, as_bf(p0[1]), o_acc[0][dt]);
        o_acc[1][dt] = mfma16(vg0, as_bf(p1[0]), o_acc[1][dt]);
        o_acc[1][dt] = mfma16(vg1, as_bf(p1[1]), o_acc[1][dt]);
    };

    stage(0, 0);
    stage(1, 1);

    for (int t = 0; t < 32; t++) {
        const int sl = t & 3;
        if (t < 30) stage(t + 2, (t + 2) & 3);
        if (t < 30)
            __builtin_amdgcn_s_waitcnt(WAITCNT_VM(8));   // drain S(t), keep S(t+1),S(t+2)
        else if (t == 30)
            __builtin_amdgcn_s_waitcnt(WAITCNT_VM(4));   // drain S(30), keep S(31)
        else
            __builtin_amdgcn_s_waitcnt(WAITCNT_VM(0));   // drain S(31)
        __builtin_amdgcn_s_barrier();                    // all waves' S(t) landed

        const unsigned short* kb_ = kbuf + sl * 4096;
        const unsigned short* vb_ = vbuf + sl * 4096;

        // QK^T with sp4 of the previous nt-group interleaved (TRANS under MFMA)
        floatx4 s0[4], s1[4];
        short4v u0[4], u1[4];
        #pragma unroll
        for (int nt = 0; nt < 4; nt++) {
            const unsigned short* kp = kb_ + (nt * 16 + lrow) * 64;
            bf16x8 ka = *(const bf16x8*)(kp + ((lq ^ sw) * 8));
            bf16x8 kb2 = *(const bf16x8*)(kp + (((lq + 4) ^ sw) * 8));
            floatx4 c0 = {-EXP2_SHIFT, -EXP2_SHIFT, -EXP2_SHIFT, -EXP2_SHIFT};
            floatx4 c1 = c0;
            c0 = mfma16(ka, qf[0][0], c0);
            c0 = mfma16(kb2, qf[0][1], c0);
            c1 = mfma16(ka, qf[1][0], c1);
            c1 = mfma16(kb2, qf[1][1], c1);
            s0[nt] = c0;
            s1[nt] = c1;
            if (nt > 0) {
                u0[nt - 1] = sp4(s0[nt - 1]);
                u1[nt - 1] = sp4(s1[nt - 1]);
            }
        }
        u0[3] = sp4(s0[3]);
        u1[3] = sp4(s1[3]);
        short8v pf0[2], pf1[2];
        pf0[0] = __builtin_shufflevector(u0[0], u0[1], 0, 1, 2, 3, 4, 5, 6, 7);
        pf0[1] = __builtin_shufflevector(u0[2], u0[3], 0, 1, 2, 3, 4, 5, 6, 7);
        pf1[0] = __builtin_shufflevector(u1[0], u1[1], 0, 1, 2, 3, 4, 5, 6, 7);
        pf1[1] = __builtin_shufflevector(u1[2], u1[3], 0, 1, 2, 3, 4, 5, 6, 7);
        // pure-MFMA burst: l_acc (4) + PV (16) — boost arbitration priority
        __builtin_amdgcn_s_setprio(1);
        l_acc[0] = mfma16(ones8, as_bf(pf0[0]), l_acc[0]);
        l_acc[0] = mfma16(ones8, as_bf(pf0[1]), l_acc[0]);
        l_acc[1] = mfma16(ones8, as_bf(pf1[0]), l_acc[1]);
        l_acc[1] = mfma16(ones8, as_bf(pf1[1]), l_acc[1]);
        #pragma unroll
        for (int dt = 0; dt < 4; dt++) pv_dt(vb_, dt, pf0, pf1);
        __builtin_amdgcn_s_setprio(0);
        // no trailing barrier: ring-4 slot discipline covers restage safety
    }

    int h = bh & 15, b = bh >> 4;
    #pragma unroll
    for (int qt = 0; qt < 2; qt++) {
        float rl2 = 1.0f / l_acc[qt][0];
        int i = i0 + w * 32 + qt * 16 + lrow;
        unsigned short* orow = att + ((long)(b * T_SEQ + i)) * D_MODEL + h * 64;
        #pragma unroll
        for (int dt = 0; dt < 4; dt++) {
            uint2 o;
            o.x = pack2_bf16(o_acc[qt][dt][0] * rl2, o_acc[qt][dt][1] * rl2);
            o.y = pack2_bf16(o_acc[qt][dt][2] * rl2, o_acc[qt][dt][3] * rl2);
            *(uint2*)(orow + dt * 16 + lq * 4) = o;
        }
    }
}

// ---------------- LayerNorm in-place on d_out ----------------
__global__ __launch_bounds__(256) void k_ln(float* __restrict__ io,
                                            const float* __restrict__ gamma,
                                            const float* __restrict__ beta) {
    int row = blockIdx.x, t = threadIdx.x;
    float* p = io + (long)row * D_MODEL + t * 4;
    float4 v = *(float4*)p;
    float s = v.x + v.y + v.z + v.w;
    float ss = v.x * v.x + v.y * v.y + v.z * v.z + v.w * v.w;
    #pragma unroll
    for (int m = 1; m < 64; m <<= 1) {
        s += __shfl_xor(s, m);
        ss += __shfl_xor(ss, m);
    }
    __shared__ float red[8];
    if ((t & 63) == 0) { red[t >> 6] = s; red[4 + (t >> 6)] = ss; }
    __syncthreads();
    s = red[0] + red[1] + red[2] + red[3];
    ss = red[4] + red[5] + red[6] + red[7];
    float mu = s * (1.0f / 1024.0f);
    float var = ss * (1.0f / 1024.0f) - mu * mu;
    float rstd = rsqrtf(var + 1e-5f);
    float4 g = *(const float4*)(gamma + t * 4);
    float4 be = *(const float4*)(beta + t * 4);
    float4 o;
    o.x = (v.x - mu) * rstd * g.x + be.x;
    o.y = (v.y - mu) * rstd * g.y + be.y;
    o.z = (v.z - mu) * rstd * g.z + be.z;
    o.w = (v.w - mu) * rstd * g.w + be.w;
    *(float4*)p = o;
}

extern "C" void kernel_launch(void* const* d_in, const int* in_sizes, int n_in,
                              void* d_out, int out_size, void* d_ws, size_t ws_size,
                              hipStream_t stream) {
    const float* x = (const float*)d_in[0];
    const float* Wq = (const float*)d_in[1];
    const float* bq = (const float*)d_in[2];
    const float* Wk = (const float*)d_in[3];
    const float* bk = (const float*)d_in[4];
    const float* Wv = (const float*)d_in[5];
    const float* bv = (const float*)d_in[6];
    const float* Wo = (const float*)d_in[7];
    const float* bo = (const float*)d_in[8];
    const float* gamma = (const float*)d_in[9];
    const float* beta = (const float*)d_in[10];
    float* out = (float*)d_out;

    char* ws = (char*)d_ws;
    unsigned short* x_bf = (unsigned short*)(ws);                       // 0-8 MB (reused as att)
    unsigned short* wqkv_bf = (unsigned short*)(ws + ((size_t)8 << 20));// 8-14 MB
    unsigned short* wo_bf = (unsigned short*)(ws + ((size_t)14 << 20)); // 14-16 MB
    unsigned short* qkv_ws = (unsigned short*)(ws + ((size_t)16 << 20));// 16-40 MB (q|k|vt)
    unsigned short* att = x_bf;  // alias: x_bf dead after QKV GEMM

    unsigned short* q_ws = qkv_ws;
    unsigned short* k_ws = qkv_ws + (size_t)32 * T_SEQ * DH;
    unsigned short* vtg = qkv_ws + (size_t)64 * T_SEQ * DH;

    k_conv_all<<<8192, 256, 0, stream>>>(x, Wq, Wk, Wv, Wo, x_bf, wqkv_bf, wo_bf);

    // fused QKV GEMM: 256x192 tiles, N = 3072, grid 256 (16x16, XCD-interleaved)
    k_qkv256<<<256, 512, 0, stream>>>(x_bf, wqkv_bf, bq, bk, bv, qkv_ws, vtg);

    k_attn<<<512, 256, 0, stream>>>(q_ws, k_ws, vtg, att);

    // O-projection + bias + residual: N = 1024, 1D grid with XCD swizzle
    k_gemm<64, 1><<<512, 256, 0, stream>>>(
        att, wo_bf, bo, x, out);

    k_ln<<<NROWS, 256, 0, stream>>>(out, gamma, beta);
}